// Round 14
// baseline (138.702 us; speedup 1.0000x reference)
//
#include <hip/hip_runtime.h>
#include <hip/hip_bf16.h>
#include <math.h>

#define BATCH   4
#define NATOMS  2048
#define MNEIGH  100
#define NFEAT   42
#define H1      64
#define H2      32
#define NPAIR   (MNEIGH * NFEAT)        // 4200 (m,f) pairs per atom
#define NA      2                       // atoms per wave (mlp)

typedef float f32x4 __attribute__((ext_vector_type(4)));

__device__ __forceinline__ float softplus_f(float z) {
    if (z > 20.f) return z;
    return log1pf(expf(z));
}

__device__ __forceinline__ float sigmoid_f(float z) {
    return 1.f / (1.f + expf(-z));
}

// Wave-uniform broadcast from a compile-time lane: v_readlane_b32 (VALU pipe,
// lands in SGPR) instead of __shfl's ds_bpermute (LDS pipe).
__device__ __forceinline__ float rdl(float v, int lane) {
    return __builtin_bit_cast(float,
        __builtin_amdgcn_readlane(__builtin_bit_cast(int, v), lane));
}

// ---------------------------------------------------------------------------
// Kernel 1: per-atom MLP + analytic dE/dx. 4 waves x 2 atoms-in-parallel,
// readlane broadcasts. (R12 champion, byte-identical; dE rows stride 42.)
// ---------------------------------------------------------------------------
__global__ __launch_bounds__(256) void mlp_kernel(
    const float* __restrict__ image,
    const float* __restrict__ W0, const float* __restrict__ b0,
    const float* __restrict__ W1, const float* __restrict__ b1,
    const float* __restrict__ W2, const float* __restrict__ b2,
    float* __restrict__ Ei_out,      // [B*N]
    float* __restrict__ dE)          // [B*N, F]
{
    __shared__ float sW0 [H1 * NFEAT];   // [h][f]  (dE pass)
    __shared__ float sW0T[NFEAT * H1];   // [f][h]  (z0 pass)
    __shared__ float sW1 [H2 * H1];      // [h2][h] (g1 pass)
    __shared__ float sW1T[H1 * H2];      // [h][h2] (z1 pass)
    __shared__ float sW2[H2];
    __shared__ float sb0[H1];
    __shared__ float sb1[H2];

    const int tid = threadIdx.x;
    for (int i = tid; i < H1 * NFEAT; i += 256) {
        const float v = W0[i];
        sW0[i] = v;
        const int h = i / NFEAT, f = i - h * NFEAT;
        sW0T[f * H1 + h] = v;
    }
    for (int i = tid; i < H2 * H1; i += 256) {
        const float v = W1[i];
        sW1[i] = v;
        const int h2 = i >> 6, h = i & 63;
        sW1T[h * H2 + h2] = v;
    }
    if (tid < H2) { sW2[tid] = W2[tid]; sb1[tid] = b1[tid]; }
    if (tid < H1) sb0[tid] = b0[tid];
    const float bias2 = b2[0];
    __syncthreads();    // the ONLY barrier

    const int wave = tid >> 6;
    const int lane = tid & 63;
    const int l2   = lane & 31;
    const int lf   = (lane < NFEAT) ? lane : NFEAT - 1;
    const int ga0  = blockIdx.x * (4 * NA) + wave * NA;   // NA atoms per wave

    float img[NA];
    #pragma unroll
    for (int a = 0; a < NA; ++a)
        img[a] = (lane < NFEAT) ? image[(size_t)(ga0 + a) * NFEAT + lane] : 0.f;

    float z0a[NA], z0b[NA];
    #pragma unroll
    for (int a = 0; a < NA; ++a) { z0a[a] = sb0[lane]; z0b[a] = 0.f; }
    #pragma unroll
    for (int f = 0; f < NFEAT; f += 2) {
        const float wA = sW0T[f * H1 + lane];
        const float wB = sW0T[(f + 1) * H1 + lane];
        #pragma unroll
        for (int a = 0; a < NA; ++a) {
            z0a[a] = fmaf(rdl(img[a], f),     wA, z0a[a]);
            z0b[a] = fmaf(rdl(img[a], f + 1), wB, z0b[a]);
        }
    }
    float L0[NA], d0[NA];
    #pragma unroll
    for (int a = 0; a < NA; ++a) {
        const float z = z0a[a] + z0b[a];
        L0[a] = softplus_f(z);
        d0[a] = sigmoid_f(z);
    }

    float z1a[NA], z1b[NA];
    #pragma unroll
    for (int a = 0; a < NA; ++a) { z1a[a] = sb1[l2]; z1b[a] = 0.f; }
    #pragma unroll
    for (int h = 0; h < H1; h += 2) {
        const float wA = sW1T[h * H2 + l2];
        const float wB = sW1T[(h + 1) * H2 + l2];
        #pragma unroll
        for (int a = 0; a < NA; ++a) {
            z1a[a] = fmaf(rdl(L0[a], h),     wA, z1a[a]);
            z1b[a] = fmaf(rdl(L0[a], h + 1), wB, z1b[a]);
        }
    }
    const float w2 = sW2[l2];
    float d1[NA];
    #pragma unroll
    for (int a = 0; a < NA; ++a) {
        const float z = z1a[a] + z1b[a];
        const float L1 = softplus_f(z);
        d1[a] = sigmoid_f(z);
        float ei = (lane < H2) ? L1 * w2 : 0.f;
        #pragma unroll
        for (int off = 16; off > 0; off >>= 1) ei += __shfl_down(ei, off, 64);
        if (lane == 0) Ei_out[ga0 + a] = ei + bias2;
    }

    float g2v[NA];
    #pragma unroll
    for (int a = 0; a < NA; ++a) g2v[a] = d1[a] * w2;   // lanes 32-63 duplicate
    float g1a[NA], g1b[NA];
    #pragma unroll
    for (int a = 0; a < NA; ++a) { g1a[a] = 0.f; g1b[a] = 0.f; }
    #pragma unroll
    for (int h2 = 0; h2 < H2; h2 += 2) {
        const float wA = sW1[h2 * H1 + lane];
        const float wB = sW1[(h2 + 1) * H1 + lane];
        #pragma unroll
        for (int a = 0; a < NA; ++a) {
            g1a[a] = fmaf(rdl(g2v[a], h2),     wA, g1a[a]);
            g1b[a] = fmaf(rdl(g2v[a], h2 + 1), wB, g1b[a]);
        }
    }
    float g1[NA];
    #pragma unroll
    for (int a = 0; a < NA; ++a) g1[a] = (g1a[a] + g1b[a]) * d0[a];

    float sa[NA], sb[NA];
    #pragma unroll
    for (int a = 0; a < NA; ++a) { sa[a] = 0.f; sb[a] = 0.f; }
    #pragma unroll
    for (int h = 0; h < H1; h += 2) {
        const float wA = sW0[h * NFEAT + lf];
        const float wB = sW0[(h + 1) * NFEAT + lf];
        #pragma unroll
        for (int a = 0; a < NA; ++a) {
            sa[a] = fmaf(rdl(g1[a], h),     wA, sa[a]);
            sb[a] = fmaf(rdl(g1[a], h + 1), wB, sb[a]);
        }
    }
    if (lane < NFEAT) {
        #pragma unroll
        for (int a = 0; a < NA; ++a)
            dE[(size_t)(ga0 + a) * NFEAT + lane] = sa[a] + sb[a];
    }
}

// ---------------------------------------------------------------------------
// Kernel 2: Etot[b] = sum_n Ei[b,n]  (unchanged)
// ---------------------------------------------------------------------------
__global__ __launch_bounds__(256) void etot_kernel(
    const float* __restrict__ Ei, float* __restrict__ Etot)
{
    const int b = blockIdx.x;
    const int tid = threadIdx.x;
    float s = 0.f;
    for (int n = tid; n < NATOMS; n += 256) s += Ei[(size_t)b * NATOMS + n];
    #pragma unroll
    for (int off = 32; off > 0; off >>= 1) s += __shfl_down(s, off, 64);
    __shared__ float rb[4];
    if ((tid & 63) == 0) rb[tid >> 6] = s;
    __syncthreads();
    if (tid == 0) Etot[b] = rb[0] + rb[1] + rb[2] + rb[3];
}

// ---------------------------------------------------------------------------
// Kernel 3: force — R11/R12 structure (wave-private staging, zero barriers,
// even-m chunks, gather-ahead pipeline, scalar gather). ONLY change this
// round: dfeat stream loads are NON-TEMPORAL (read-once data; MUBUF nt) so
// the 413 MB stream stops evicting the hot 1.4 MB dE table from L2 — the
// gather then runs at L2-hit latency instead of HBM-miss latency.
// Force store also NT (write-once).
// ---------------------------------------------------------------------------
#define F_GATHER(M0, NW)                                                     \
    {                                                                        \
        _Pragma("unroll")                                                    \
        for (int t = 0; t < 18; ++t) {                                       \
            const int j = lane + 64 * t;                                     \
            float v = 0.f;                                                   \
            if (j < (NW)) {                                                  \
                const int ml = j / NFEAT;                                    \
                const int f  = j - ml * NFEAT;                               \
                const int nb = snbr[wave][(M0) + ml];                        \
                const float d =                                              \
                    dErow[(size_t)((nb > 0) ? nb - 1 : 0) * NFEAT + f];      \
                v = (nb > 0) ? d : 0.f;                                      \
            }                                                                \
            gv[t] = v;                                                       \
        }                                                                    \
    }

#define F_SPILL(NW)                                                          \
    {                                                                        \
        _Pragma("unroll")                                                    \
        for (int t = 0; t < 18; ++t) {                                       \
            const int j = lane + 64 * t;                                     \
            if (j < (NW)) swt[wave][j] = gv[t];                              \
        }                                                                    \
    }

#define F_STREAM(M0, NG)                                                     \
    {                                                                        \
        const f32x4* __restrict__ dfb4 =                                     \
            (const f32x4*)(dfA + (size_t)(M0) * (NFEAT * 3));                \
        const float4* __restrict__ s4 = (const float4*)swt[wave];            \
        for (int g = lane; g < (NG); g += 64) {                              \
            const float4 w  = s4[g];                                         \
            const f32x4 v0 = __builtin_nontemporal_load(dfb4 + 3 * g);       \
            const f32x4 v1 = __builtin_nontemporal_load(dfb4 + 3 * g + 1);   \
            const f32x4 v2 = __builtin_nontemporal_load(dfb4 + 3 * g + 2);   \
            a0 = fmaf(v0.x, w.x, a0); a1 = fmaf(v0.y, w.x, a1);              \
            a2 = fmaf(v0.z, w.x, a2);                                        \
            a0 = fmaf(v0.w, w.y, a0); a1 = fmaf(v1.x, w.y, a1);              \
            a2 = fmaf(v1.y, w.y, a2);                                        \
            a0 = fmaf(v1.z, w.z, a0); a1 = fmaf(v1.w, w.z, a1);              \
            a2 = fmaf(v2.x, w.z, a2);                                        \
            a0 = fmaf(v2.y, w.w, a0); a1 = fmaf(v2.z, w.w, a1);              \
            a2 = fmaf(v2.w, w.w, a2);                                        \
        }                                                                    \
    }

__global__ __launch_bounds__(256) void force_kernel(
    const float* __restrict__ dfeat,
    const int*   __restrict__ neighbor,
    const float* __restrict__ dE,
    float* __restrict__ force)
{
    __shared__ float swt[4][1092];          // per-wave chunk weights (17.5 KB)
    __shared__ int   snbr[4][MNEIGH];       // per-wave neighbor row (1.6 KB)

    const int tid  = threadIdx.x;
    const int wave = tid >> 6, lane = tid & 63;
    const int ga   = blockIdx.x * 4 + wave;     // this wave's atom
    const int rowbase = (ga >> 11) * NATOMS;    // batch row offset (4 | 2048)

    // wave-private neighbor staging (no barrier; lgkmcnt orders it)
    if (lane < 50) {
        snbr[wave][lane]      = neighbor[(size_t)ga * MNEIGH + lane];
        snbr[wave][lane + 50] = neighbor[(size_t)ga * MNEIGH + lane + 50];
    }

    const float* __restrict__ dErow = dE + (size_t)rowbase * NFEAT;
    const float* __restrict__ dfA   = dfeat + (size_t)ga * (NPAIR * 3);

    float gv[18];
    float a0 = 0.f, a1 = 0.f, a2 = 0.f;

    // chunks (m0, mc): (0,26)(26,26)(52,26)(78,22); NW = mc*42, NG = NW/4
    F_GATHER(0, 1092);  F_SPILL(1092);
    F_GATHER(26, 1092); F_STREAM(0, 273);  F_SPILL(1092);
    F_GATHER(52, 1092); F_STREAM(26, 273); F_SPILL(1092);
    F_GATHER(78, 924);  F_STREAM(52, 273); F_SPILL(924);
    F_STREAM(78, 231);

    // pure-shfl wave reduce, lane 0 stores
    #pragma unroll
    for (int off = 32; off > 0; off >>= 1) {
        a0 += __shfl_down(a0, off, 64);
        a1 += __shfl_down(a1, off, 64);
        a2 += __shfl_down(a2, off, 64);
    }
    if (lane == 0) {
        __builtin_nontemporal_store(a0, &force[(size_t)ga * 3 + 0]);
        __builtin_nontemporal_store(a1, &force[(size_t)ga * 3 + 1]);
        __builtin_nontemporal_store(a2, &force[(size_t)ga * 3 + 2]);
    }
}

// ---------------------------------------------------------------------------
extern "C" void kernel_launch(void* const* d_in, const int* in_sizes, int n_in,
                              void* d_out, int out_size, void* d_ws, size_t ws_size,
                              hipStream_t stream) {
    const float* image = (const float*)d_in[0];
    const float* dfeat = (const float*)d_in[1];
    // d_in[2] = Egroup_weight (unused by reference), d_in[3] = divider (unused)
    const float* W0 = (const float*)d_in[4];
    const float* b0 = (const float*)d_in[5];
    const float* W1 = (const float*)d_in[6];
    const float* b1 = (const float*)d_in[7];
    const float* W2 = (const float*)d_in[8];
    const float* b2 = (const float*)d_in[9];
    const int*   neighbor = (const int*)d_in[10];

    float* out   = (float*)d_out;
    float* Etot  = out;                          // [B,1]   -> 4
    float* Ei    = out + BATCH;                  // [B,N,1] -> 8192
    float* force = out + BATCH + BATCH * NATOMS; // [B,N,3] -> 24576
    float* dE    = (float*)d_ws;                 // [B,N,F] floats in workspace

    mlp_kernel<<<BATCH * NATOMS / (4 * NA), 256, 0, stream>>>(
        image, W0, b0, W1, b1, W2, b2, Ei, dE);
    etot_kernel<<<BATCH, 256, 0, stream>>>(Ei, Etot);
    force_kernel<<<BATCH * NATOMS / 4, 256, 0, stream>>>(dfeat, neighbor, dE, force);
}

// Round 15
// 106.202 us; speedup vs baseline: 1.3060x; 1.3060x over previous
//
#include <hip/hip_runtime.h>
#include <hip/hip_bf16.h>
#include <math.h>

#define BATCH   4
#define NATOMS  2048
#define MNEIGH  100
#define NFEAT   42
#define H1      64
#define H2      32
#define NPAIR   (MNEIGH * NFEAT)        // 4200 (m,f) pairs per atom
#define NA      2                       // atoms per wave (mlp)

__device__ __forceinline__ float softplus_f(float z) {
    if (z > 20.f) return z;
    return log1pf(expf(z));
}

__device__ __forceinline__ float sigmoid_f(float z) {
    return 1.f / (1.f + expf(-z));
}

// Wave-uniform broadcast from a compile-time lane: v_readlane_b32 (VALU pipe,
// lands in SGPR) instead of __shfl's ds_bpermute (LDS pipe).
__device__ __forceinline__ float rdl(float v, int lane) {
    return __builtin_bit_cast(float,
        __builtin_amdgcn_readlane(__builtin_bit_cast(int, v), lane));
}

// ---------------------------------------------------------------------------
// Kernel 1: per-atom MLP + analytic dE/dx. 4 waves x 2 atoms-in-parallel,
// readlane broadcasts. (R12 champion, byte-identical.)
// ---------------------------------------------------------------------------
__global__ __launch_bounds__(256) void mlp_kernel(
    const float* __restrict__ image,
    const float* __restrict__ W0, const float* __restrict__ b0,
    const float* __restrict__ W1, const float* __restrict__ b1,
    const float* __restrict__ W2, const float* __restrict__ b2,
    float* __restrict__ Ei_out,      // [B*N]
    float* __restrict__ dE)          // [B*N, F]
{
    __shared__ float sW0 [H1 * NFEAT];   // [h][f]  (dE pass)
    __shared__ float sW0T[NFEAT * H1];   // [f][h]  (z0 pass)
    __shared__ float sW1 [H2 * H1];      // [h2][h] (g1 pass)
    __shared__ float sW1T[H1 * H2];      // [h][h2] (z1 pass)
    __shared__ float sW2[H2];
    __shared__ float sb0[H1];
    __shared__ float sb1[H2];

    const int tid = threadIdx.x;
    for (int i = tid; i < H1 * NFEAT; i += 256) {
        const float v = W0[i];
        sW0[i] = v;
        const int h = i / NFEAT, f = i - h * NFEAT;
        sW0T[f * H1 + h] = v;
    }
    for (int i = tid; i < H2 * H1; i += 256) {
        const float v = W1[i];
        sW1[i] = v;
        const int h2 = i >> 6, h = i & 63;
        sW1T[h * H2 + h2] = v;
    }
    if (tid < H2) { sW2[tid] = W2[tid]; sb1[tid] = b1[tid]; }
    if (tid < H1) sb0[tid] = b0[tid];
    const float bias2 = b2[0];
    __syncthreads();    // the ONLY barrier

    const int wave = tid >> 6;
    const int lane = tid & 63;
    const int l2   = lane & 31;
    const int lf   = (lane < NFEAT) ? lane : NFEAT - 1;
    const int ga0  = blockIdx.x * (4 * NA) + wave * NA;   // NA atoms per wave

    float img[NA];
    #pragma unroll
    for (int a = 0; a < NA; ++a)
        img[a] = (lane < NFEAT) ? image[(size_t)(ga0 + a) * NFEAT + lane] : 0.f;

    float z0a[NA], z0b[NA];
    #pragma unroll
    for (int a = 0; a < NA; ++a) { z0a[a] = sb0[lane]; z0b[a] = 0.f; }
    #pragma unroll
    for (int f = 0; f < NFEAT; f += 2) {
        const float wA = sW0T[f * H1 + lane];
        const float wB = sW0T[(f + 1) * H1 + lane];
        #pragma unroll
        for (int a = 0; a < NA; ++a) {
            z0a[a] = fmaf(rdl(img[a], f),     wA, z0a[a]);
            z0b[a] = fmaf(rdl(img[a], f + 1), wB, z0b[a]);
        }
    }
    float L0[NA], d0[NA];
    #pragma unroll
    for (int a = 0; a < NA; ++a) {
        const float z = z0a[a] + z0b[a];
        L0[a] = softplus_f(z);
        d0[a] = sigmoid_f(z);
    }

    float z1a[NA], z1b[NA];
    #pragma unroll
    for (int a = 0; a < NA; ++a) { z1a[a] = sb1[l2]; z1b[a] = 0.f; }
    #pragma unroll
    for (int h = 0; h < H1; h += 2) {
        const float wA = sW1T[h * H2 + l2];
        const float wB = sW1T[(h + 1) * H2 + l2];
        #pragma unroll
        for (int a = 0; a < NA; ++a) {
            z1a[a] = fmaf(rdl(L0[a], h),     wA, z1a[a]);
            z1b[a] = fmaf(rdl(L0[a], h + 1), wB, z1b[a]);
        }
    }
    const float w2 = sW2[l2];
    float d1[NA];
    #pragma unroll
    for (int a = 0; a < NA; ++a) {
        const float z = z1a[a] + z1b[a];
        const float L1 = softplus_f(z);
        d1[a] = sigmoid_f(z);
        float ei = (lane < H2) ? L1 * w2 : 0.f;
        #pragma unroll
        for (int off = 16; off > 0; off >>= 1) ei += __shfl_down(ei, off, 64);
        if (lane == 0) Ei_out[ga0 + a] = ei + bias2;
    }

    float g2v[NA];
    #pragma unroll
    for (int a = 0; a < NA; ++a) g2v[a] = d1[a] * w2;   // lanes 32-63 duplicate
    float g1a[NA], g1b[NA];
    #pragma unroll
    for (int a = 0; a < NA; ++a) { g1a[a] = 0.f; g1b[a] = 0.f; }
    #pragma unroll
    for (int h2 = 0; h2 < H2; h2 += 2) {
        const float wA = sW1[h2 * H1 + lane];
        const float wB = sW1[(h2 + 1) * H1 + lane];
        #pragma unroll
        for (int a = 0; a < NA; ++a) {
            g1a[a] = fmaf(rdl(g2v[a], h2),     wA, g1a[a]);
            g1b[a] = fmaf(rdl(g2v[a], h2 + 1), wB, g1b[a]);
        }
    }
    float g1[NA];
    #pragma unroll
    for (int a = 0; a < NA; ++a) g1[a] = (g1a[a] + g1b[a]) * d0[a];

    float sa[NA], sb[NA];
    #pragma unroll
    for (int a = 0; a < NA; ++a) { sa[a] = 0.f; sb[a] = 0.f; }
    #pragma unroll
    for (int h = 0; h < H1; h += 2) {
        const float wA = sW0[h * NFEAT + lf];
        const float wB = sW0[(h + 1) * NFEAT + lf];
        #pragma unroll
        for (int a = 0; a < NA; ++a) {
            sa[a] = fmaf(rdl(g1[a], h),     wA, sa[a]);
            sb[a] = fmaf(rdl(g1[a], h + 1), wB, sb[a]);
        }
    }
    if (lane < NFEAT) {
        #pragma unroll
        for (int a = 0; a < NA; ++a)
            dE[(size_t)(ga0 + a) * NFEAT + lane] = sa[a] + sb[a];
    }
}

// ---------------------------------------------------------------------------
// Kernel 2: Etot[b] = sum_n Ei[b,n]  (unchanged)
// ---------------------------------------------------------------------------
__global__ __launch_bounds__(256) void etot_kernel(
    const float* __restrict__ Ei, float* __restrict__ Etot)
{
    const int b = blockIdx.x;
    const int tid = threadIdx.x;
    float s = 0.f;
    for (int n = tid; n < NATOMS; n += 256) s += Ei[(size_t)b * NATOMS + n];
    #pragma unroll
    for (int off = 32; off > 0; off >>= 1) s += __shfl_down(s, off, 64);
    __shared__ float rb[4];
    if ((tid & 63) == 0) rb[tid >> 6] = s;
    __syncthreads();
    if (tid == 0) Etot[b] = rb[0] + rb[1] + rb[2] + rb[3];
}

// ---------------------------------------------------------------------------
// Kernel 3: force — R11/R12 champion, byte-identical. Wave-private staging,
// zero barriers, even-m chunks (26,26,26,22), gather-ahead pipeline,
// scalar gather, plain cached float4 stream.
// ---------------------------------------------------------------------------
#define F_GATHER(M0, NW)                                                     \
    {                                                                        \
        _Pragma("unroll")                                                    \
        for (int t = 0; t < 18; ++t) {                                       \
            const int j = lane + 64 * t;                                     \
            float v = 0.f;                                                   \
            if (j < (NW)) {                                                  \
                const int ml = j / NFEAT;                                    \
                const int f  = j - ml * NFEAT;                               \
                const int nb = snbr[wave][(M0) + ml];                        \
                const float d =                                              \
                    dErow[(size_t)((nb > 0) ? nb - 1 : 0) * NFEAT + f];      \
                v = (nb > 0) ? d : 0.f;                                      \
            }                                                                \
            gv[t] = v;                                                       \
        }                                                                    \
    }

#define F_SPILL(NW)                                                          \
    {                                                                        \
        _Pragma("unroll")                                                    \
        for (int t = 0; t < 18; ++t) {                                       \
            const int j = lane + 64 * t;                                     \
            if (j < (NW)) swt[wave][j] = gv[t];                              \
        }                                                                    \
    }

#define F_STREAM(M0, NG)                                                     \
    {                                                                        \
        const float4* __restrict__ dfb4 =                                    \
            (const float4*)(dfA + (size_t)(M0) * (NFEAT * 3));               \
        const float4* __restrict__ s4 = (const float4*)swt[wave];            \
        for (int g = lane; g < (NG); g += 64) {                              \
            const float4 w  = s4[g];                                         \
            const float4 v0 = dfb4[3 * g];                                   \
            const float4 v1 = dfb4[3 * g + 1];                               \
            const float4 v2 = dfb4[3 * g + 2];                               \
            a0 = fmaf(v0.x, w.x, a0); a1 = fmaf(v0.y, w.x, a1);              \
            a2 = fmaf(v0.z, w.x, a2);                                        \
            a0 = fmaf(v0.w, w.y, a0); a1 = fmaf(v1.x, w.y, a1);              \
            a2 = fmaf(v1.y, w.y, a2);                                        \
            a0 = fmaf(v1.z, w.z, a0); a1 = fmaf(v1.w, w.z, a1);              \
            a2 = fmaf(v2.x, w.z, a2);                                        \
            a0 = fmaf(v2.y, w.w, a0); a1 = fmaf(v2.z, w.w, a1);              \
            a2 = fmaf(v2.w, w.w, a2);                                        \
        }                                                                    \
    }

__global__ __launch_bounds__(256) void force_kernel(
    const float* __restrict__ dfeat,
    const int*   __restrict__ neighbor,
    const float* __restrict__ dE,
    float* __restrict__ force)
{
    __shared__ float swt[4][1092];          // per-wave chunk weights (17.5 KB)
    __shared__ int   snbr[4][MNEIGH];       // per-wave neighbor row (1.6 KB)

    const int tid  = threadIdx.x;
    const int wave = tid >> 6, lane = tid & 63;
    const int ga   = blockIdx.x * 4 + wave;     // this wave's atom
    const int rowbase = (ga >> 11) * NATOMS;    // batch row offset (4 | 2048)

    // wave-private neighbor staging (no barrier; lgkmcnt orders it)
    if (lane < 50) {
        snbr[wave][lane]      = neighbor[(size_t)ga * MNEIGH + lane];
        snbr[wave][lane + 50] = neighbor[(size_t)ga * MNEIGH + lane + 50];
    }

    const float* __restrict__ dErow = dE + (size_t)rowbase * NFEAT;
    const float* __restrict__ dfA   = dfeat + (size_t)ga * (NPAIR * 3);

    float gv[18];
    float a0 = 0.f, a1 = 0.f, a2 = 0.f;

    // chunks (m0, mc): (0,26)(26,26)(52,26)(78,22); NW = mc*42, NG = NW/4
    F_GATHER(0, 1092);  F_SPILL(1092);
    F_GATHER(26, 1092); F_STREAM(0, 273);  F_SPILL(1092);
    F_GATHER(52, 1092); F_STREAM(26, 273); F_SPILL(1092);
    F_GATHER(78, 924);  F_STREAM(52, 273); F_SPILL(924);
    F_STREAM(78, 231);

    // pure-shfl wave reduce, lane 0 stores
    #pragma unroll
    for (int off = 32; off > 0; off >>= 1) {
        a0 += __shfl_down(a0, off, 64);
        a1 += __shfl_down(a1, off, 64);
        a2 += __shfl_down(a2, off, 64);
    }
    if (lane == 0) {
        force[(size_t)ga * 3 + 0] = a0;
        force[(size_t)ga * 3 + 1] = a1;
        force[(size_t)ga * 3 + 2] = a2;
    }
}

// ---------------------------------------------------------------------------
extern "C" void kernel_launch(void* const* d_in, const int* in_sizes, int n_in,
                              void* d_out, int out_size, void* d_ws, size_t ws_size,
                              hipStream_t stream) {
    const float* image = (const float*)d_in[0];
    const float* dfeat = (const float*)d_in[1];
    // d_in[2] = Egroup_weight (unused by reference), d_in[3] = divider (unused)
    const float* W0 = (const float*)d_in[4];
    const float* b0 = (const float*)d_in[5];
    const float* W1 = (const float*)d_in[6];
    const float* b1 = (const float*)d_in[7];
    const float* W2 = (const float*)d_in[8];
    const float* b2 = (const float*)d_in[9];
    const int*   neighbor = (const int*)d_in[10];

    float* out   = (float*)d_out;
    float* Etot  = out;                          // [B,1]   -> 4
    float* Ei    = out + BATCH;                  // [B,N,1] -> 8192
    float* force = out + BATCH + BATCH * NATOMS; // [B,N,3] -> 24576
    float* dE    = (float*)d_ws;                 // [B,N,F] floats in workspace

    mlp_kernel<<<BATCH * NATOMS / (4 * NA), 256, 0, stream>>>(
        image, W0, b0, W1, b1, W2, b2, Ei, dE);
    etot_kernel<<<BATCH, 256, 0, stream>>>(Ei, Etot);
    force_kernel<<<BATCH * NATOMS / 4, 256, 0, stream>>>(dfeat, neighbor, dE, force);
}